// Round 5
// baseline (513.780 us; speedup 1.0000x reference)
//
#include <hip/hip_runtime.h>
#include <hip/hip_bf16.h>
#include <cstddef>

// Problem dims
#define DN 192
#define DM 256
#define DD 1024
#define DK 65
#define OUTW 192

using f32x4 = __attribute__((ext_vector_type(4))) float;
using s16x8 = __attribute__((ext_vector_type(8))) short;

__device__ __forceinline__ float sigm(float v) { return 1.0f / (1.0f + __expf(-v)); }
__device__ __forceinline__ unsigned short f2b(float f) {
    __hip_bfloat16 h = __float2bfloat16(f);
    return *reinterpret_cast<unsigned short*>(&h);
}
__device__ __forceinline__ float b2f(unsigned short s) {
    __hip_bfloat16 h = *reinterpret_cast<__hip_bfloat16*>(&s);
    return __bfloat162float(h);
}

// ---------------- MFMA path ws layout (float offsets) ----------------
#define OFF_QF   0u
#define OFF_A2   65536u
#define OFF_A4   131072u
#define OFF_A8   196608u
#define OFF_A16  262144u
#define OFF_A32  327680u
#define OFF_A64  393216u
#define OFF_QB   458752u
#define OFF_W0B  491520u
#define OFF_P8B  524288u
#define OFF_P64B 557056u
#define OFF_SA1  589824u      // bf16 [128][192][256] C-frag = 3145728 float-slots
#define OFF_SA2  3735552u     // f32  [16][192][256] C-frag  = 786432 floats
#define MFMA_NEED_BYTES 18087936ULL

// Build: Qf fp32 [m][c] = W[c][m][1]; QB/W0B bf16 B-frag lane tables.
// B-frag entry e=(ct,ks,lane): 8 bf16, value(j) = M[ks*32+(l>>4)*8+j][ct*16+(l&15)]
__global__ __launch_bounds__(256) void k_prep2(const float* __restrict__ W,
                                               float* __restrict__ ws) {
    const int bid = blockIdx.x, t = threadIdx.x;
    if (bid < 256) {
        const int c = bid, m = t;
        ws[OFF_QF + m * 256 + c] = W[(size_t)(c * 256 + m) * 2 + 1];
    } else {
        const int which = (bid - 256) >> 5;           // 0 -> QB, 1 -> W0B
        const int e = ((bid - 256) & 31) * 256 + t;   // 0..8191
        const int ct = e >> 9, ks = (e >> 6) & 7, l = e & 63;
        const int c = ct * 16 + (l & 15);
        const int mb = ks * 32 + (l >> 4) * 8;
        s16x8 pk;
#pragma unroll
        for (int j = 0; j < 8; ++j)
            pk[j] = (short)f2b(W[(size_t)(c * 256 + mb + j) * 2 + (which ? 0 : 1)]);
        float* dst = ws + (which ? OFF_W0B : OFF_QB);
        reinterpret_cast<s16x8*>(dst)[e] = pk;
    }
}

// C = A*A (fp32 256x256, plain [m][c] layout). One output row per WG.
// If bfrag != null, also emit C's bf16 B-frag table entries for row r0.
__global__ __launch_bounds__(256) void k_sq256(const float* __restrict__ A,
                                               float* __restrict__ C,
                                               ushort* __restrict__ bfrag) {
    __shared__ float ar[256];
    const int r0 = blockIdx.x, k = threadIdx.x;
    ar[k] = A[r0 * 256 + k];
    __syncthreads();
    float a0 = 0.f, a1 = 0.f, a2 = 0.f, a3 = 0.f;
    for (int m = 0; m < 256; m += 8) {
        a0 += ar[m + 0] * A[(m + 0) * 256 + k] + ar[m + 4] * A[(m + 4) * 256 + k];
        a1 += ar[m + 1] * A[(m + 1) * 256 + k] + ar[m + 5] * A[(m + 5) * 256 + k];
        a2 += ar[m + 2] * A[(m + 2) * 256 + k] + ar[m + 6] * A[(m + 6) * 256 + k];
        a3 += ar[m + 3] * A[(m + 3) * 256 + k] + ar[m + 7] * A[(m + 7) * 256 + k];
    }
    const float v = (a0 + a1) + (a2 + a3);
    C[r0 * 256 + k] = v;
    if (bfrag) {
        const int entry = ((k >> 4) * 8 + (r0 >> 5)) * 64 + ((r0 >> 3) & 3) * 16 + (k & 15);
        bfrag[entry * 8 + (r0 & 7)] = f2b(v);
    }
}

// Fused phase1 + L1 scan. Grid (6 row-groups of 32, 128 d-groups of 8). 512 thr = 8 waves.
// Per step (Horner, top-down within group): acc = b + sigma(R_d) + R_d*W0^T + S*Q
// S double-buffered in LDS as bf16 A-frags; Q B-frags stationary in VGPRs;
// W0 B-frags streamed from L2; R prefetched to regs one step ahead.
// Group 127 step 0 loads h0 = NAT[:,1023,:] instead.
// Output: S_grp as bf16 C-frags to SA1[grp].
__global__ __launch_bounds__(512, 4) void k_fused(const float* __restrict__ NAT,
                                                  const float* __restrict__ bvec,
                                                  const float* __restrict__ ws,
                                                  ushort* __restrict__ SA1) {
    __shared__ short Rl[2][8][66][8];     // [rt][ks][slot(pad66)][j] : 16.9 KB
    __shared__ short Sl[2][2][8][64][8];  // [buf][rt][ks][slot][j]   : 32.8 KB
    const int rt2 = blockIdx.x;           // 0..5
    const int grp = blockIdx.y;           // 0..127
    const int tid = threadIdx.x;
    const int w = tid >> 6, l = tid & 63;
    const int n0 = rt2 * 32;
    const ushort* W0b = reinterpret_cast<const ushort*>(ws + OFF_W0B);
    const ushort* Qb  = reinterpret_cast<const ushort*>(ws + OFF_QB);

    // stationary Q B-frags (this wave's 2 col-tiles)
    s16x8 qreg[2][8];
#pragma unroll
    for (int c = 0; c < 2; ++c)
#pragma unroll
        for (int ks = 0; ks < 8; ++ks)
            qreg[c][ks] = *reinterpret_cast<const s16x8*>(Qb + (((2 * w + c) * 8 + ks) * 64 + l) * 8);

    // staging coords: thread = (row, ks-chunk, half): 16 consecutive floats
    const int srow = tid >> 4;            // 0..31
    const int sks  = (tid >> 1) & 7;
    const int shalf = tid & 1;
    const float* sbase = NAT + (size_t)(n0 + srow) * DD * DM + sks * 32 + shalf * 16;

    // prologue: load R(d_top)
    float4 rv0, rv1, rv2, rv3;
    {
        const float* p = sbase + (size_t)(grp * 8 + 7) * DM;
        rv0 = *reinterpret_cast<const float4*>(p + 0);
        rv1 = *reinterpret_cast<const float4*>(p + 4);
        rv2 = *reinterpret_cast<const float4*>(p + 8);
        rv3 = *reinterpret_cast<const float4*>(p + 12);
    }
    const float bcol0 = bvec[w * 32 + (l & 15)];
    const float bcol1 = bvec[w * 32 + 16 + (l & 15)];

    f32x4 acc[2][2];
    int cur = 0;
    for (int it = 0; it < 8; ++it) {
        const int d = grp * 8 + 7 - it;
        // write staged R (current step) to LDS A-frag layout
        {
            const int g0 = shalf * 2;
            s16x8 pk0, pk1;
            pk0[0] = (short)f2b(rv0.x); pk0[1] = (short)f2b(rv0.y);
            pk0[2] = (short)f2b(rv0.z); pk0[3] = (short)f2b(rv0.w);
            pk0[4] = (short)f2b(rv1.x); pk0[5] = (short)f2b(rv1.y);
            pk0[6] = (short)f2b(rv1.z); pk0[7] = (short)f2b(rv1.w);
            pk1[0] = (short)f2b(rv2.x); pk1[1] = (short)f2b(rv2.y);
            pk1[2] = (short)f2b(rv2.z); pk1[3] = (short)f2b(rv2.w);
            pk1[4] = (short)f2b(rv3.x); pk1[5] = (short)f2b(rv3.y);
            pk1[6] = (short)f2b(rv3.z); pk1[7] = (short)f2b(rv3.w);
            *reinterpret_cast<s16x8*>(&Rl[srow >> 4][sks][(srow & 15) + 16 * g0][0]) = pk0;
            *reinterpret_cast<s16x8*>(&Rl[srow >> 4][sks][(srow & 15) + 16 * (g0 + 1)][0]) = pk1;
        }
        // prefetch next step's R (hidden under this step's compute)
        if (it < 7) {
            const float* p = sbase + (size_t)(d - 1) * DM;
            rv0 = *reinterpret_cast<const float4*>(p + 0);
            rv1 = *reinterpret_cast<const float4*>(p + 4);
            rv2 = *reinterpret_cast<const float4*>(p + 8);
            rv3 = *reinterpret_cast<const float4*>(p + 12);
        }
        __syncthreads();

        if (grp == 127 && it == 0) {
            // v_1023 = h0 (fp32 direct)
#pragma unroll
            for (int rt = 0; rt < 2; ++rt)
#pragma unroll
                for (int c = 0; c < 2; ++c) {
                    const int col = w * 32 + c * 16 + (l & 15);
#pragma unroll
                    for (int r = 0; r < 4; ++r) {
                        const int n = n0 + rt * 16 + (l >> 4) * 4 + r;
                        acc[rt][c][r] = NAT[((size_t)n * DD + (DD - 1)) * DM + col];
                    }
                }
        } else {
            // acc = b + sigma(R) at C-frag positions
#pragma unroll
            for (int rt = 0; rt < 2; ++rt)
#pragma unroll
                for (int c = 0; c < 2; ++c) {
                    const int col = w * 32 + c * 16 + (l & 15);
                    const int ksm = col >> 5, sl = 16 * ((col >> 3) & 3), jb = col & 7;
                    const float bc = c ? bcol1 : bcol0;
#pragma unroll
                    for (int r = 0; r < 4; ++r) {
                        const int row15 = (l >> 4) * 4 + r;
                        const unsigned short sv = (unsigned short)Rl[rt][ksm][row15 + sl][jb];
                        acc[rt][c][r] = bc + sigm(b2f(sv));
                    }
                }
            // acc += R * W0^T (W0 B-frags streamed from L2)
#pragma unroll
            for (int ks = 0; ks < 8; ++ks) {
                const s16x8 gb0 = *reinterpret_cast<const s16x8*>(W0b + (((2 * w + 0) * 8 + ks) * 64 + l) * 8);
                const s16x8 gb1 = *reinterpret_cast<const s16x8*>(W0b + (((2 * w + 1) * 8 + ks) * 64 + l) * 8);
                const s16x8 a0 = *reinterpret_cast<const s16x8*>(&Rl[0][ks][l][0]);
                const s16x8 a1 = *reinterpret_cast<const s16x8*>(&Rl[1][ks][l][0]);
                acc[0][0] = __builtin_amdgcn_mfma_f32_16x16x32_bf16(a0, gb0, acc[0][0], 0, 0, 0);
                acc[0][1] = __builtin_amdgcn_mfma_f32_16x16x32_bf16(a0, gb1, acc[0][1], 0, 0, 0);
                acc[1][0] = __builtin_amdgcn_mfma_f32_16x16x32_bf16(a1, gb0, acc[1][0], 0, 0, 0);
                acc[1][1] = __builtin_amdgcn_mfma_f32_16x16x32_bf16(a1, gb1, acc[1][1], 0, 0, 0);
            }
        }
        // acc += S_old * Q
        if (it > 0) {
#pragma unroll
            for (int ks = 0; ks < 8; ++ks) {
                const s16x8 s0 = *reinterpret_cast<const s16x8*>(&Sl[cur][0][ks][l][0]);
                const s16x8 s1 = *reinterpret_cast<const s16x8*>(&Sl[cur][1][ks][l][0]);
                acc[0][0] = __builtin_amdgcn_mfma_f32_16x16x32_bf16(s0, qreg[0][ks], acc[0][0], 0, 0, 0);
                acc[0][1] = __builtin_amdgcn_mfma_f32_16x16x32_bf16(s0, qreg[1][ks], acc[0][1], 0, 0, 0);
                acc[1][0] = __builtin_amdgcn_mfma_f32_16x16x32_bf16(s1, qreg[0][ks], acc[1][0], 0, 0, 0);
                acc[1][1] = __builtin_amdgcn_mfma_f32_16x16x32_bf16(s1, qreg[1][ks], acc[1][1], 0, 0, 0);
            }
        }
        if (it < 7) {
            // S_new -> Sl[cur^1] bf16 A-frags (this wave owns ks = w)
#pragma unroll
            for (int rt = 0; rt < 2; ++rt)
#pragma unroll
                for (int c = 0; c < 2; ++c) {
                    const int col = w * 32 + c * 16 + (l & 15);
                    const int sl = 16 * ((col >> 3) & 3), jb = col & 7;
#pragma unroll
                    for (int r = 0; r < 4; ++r) {
                        const int row15 = (l >> 4) * 4 + r;
                        Sl[cur ^ 1][rt][w][row15 + sl][jb] = (short)f2b(acc[rt][c][r]);
                    }
                }
            __syncthreads();
            cur ^= 1;
        }
    }

    // S_grp -> SA1 bf16 C-frags
#pragma unroll
    for (int rt = 0; rt < 2; ++rt)
#pragma unroll
        for (int c = 0; c < 2; ++c) {
            const size_t base = (((size_t)grp * 12 + (rt2 * 2 + rt)) * 16 + (2 * w + c)) * 64 + l;
            ushort4 o;
            o.x = f2b(acc[rt][c][0]); o.y = f2b(acc[rt][c][1]);
            o.z = f2b(acc[rt][c][2]); o.w = f2b(acc[rt][c][3]);
            reinterpret_cast<ushort4*>(SA1)[base] = o;
        }
}

// Generic blocked-Horner combine (L2/L3): acc = V_top; acc = V_d + acc*Qk.
// Grid (6 row-groups of 32, ngrp). Qk B-frags stationary in regs.
__global__ __launch_bounds__(512) void k_scan(const void* __restrict__ Vin, int in_bf16,
                                              const float* __restrict__ ws, unsigned qb_off,
                                              int nsteps,
                                              void* __restrict__ OutC, int out_bf16,
                                              const float* __restrict__ xin,
                                              const float* __restrict__ W2,
                                              const float* __restrict__ b2p,
                                              float* __restrict__ outF) {
    __shared__ __align__(16) char smem[33856];
    short (*Sl)[2][8][64][8] = reinterpret_cast<short (*)[2][8][64][8]>(smem);
    float (*resl)[260]       = reinterpret_cast<float (*)[260]>(smem);   // overlays Sl
    float* w2l               = reinterpret_cast<float*>(smem + 33280);
    const int rt2 = blockIdx.x;            // 0..5
    const int grp = blockIdx.y;
    const int tid = threadIdx.x;
    const int w = tid >> 6, l = tid & 63;
    const ushort* Qb = reinterpret_cast<const ushort*>(ws + qb_off);

    s16x8 qreg[2][8];
#pragma unroll
    for (int c = 0; c < 2; ++c)
#pragma unroll
        for (int ks = 0; ks < 8; ++ks)
            qreg[c][ks] = *reinterpret_cast<const s16x8*>(Qb + (((2 * w + c) * 8 + ks) * 64 + l) * 8);

    f32x4 acc[2][2];
    int cur = 0;
    for (int it = 0; it < nsteps; ++it) {
        const int d = grp * nsteps + (nsteps - 1) - it;
#pragma unroll
        for (int rt = 0; rt < 2; ++rt)
#pragma unroll
            for (int c = 0; c < 2; ++c) {
                const size_t base = (((size_t)d * 12 + (rt2 * 2 + rt)) * 16 + (2 * w + c)) * 64 + l;
                if (in_bf16) {
                    const ushort4 v = reinterpret_cast<const ushort4*>(Vin)[base];
                    acc[rt][c][0] = b2f(v.x); acc[rt][c][1] = b2f(v.y);
                    acc[rt][c][2] = b2f(v.z); acc[rt][c][3] = b2f(v.w);
                } else {
                    acc[rt][c] = reinterpret_cast<const f32x4*>(Vin)[base];
                }
            }
        if (it > 0) {
#pragma unroll
            for (int ks = 0; ks < 8; ++ks) {
                const s16x8 a0 = *reinterpret_cast<const s16x8*>(&Sl[cur][0][ks][l][0]);
                const s16x8 a1 = *reinterpret_cast<const s16x8*>(&Sl[cur][1][ks][l][0]);
                acc[0][0] = __builtin_amdgcn_mfma_f32_16x16x32_bf16(a0, qreg[0][ks], acc[0][0], 0, 0, 0);
                acc[0][1] = __builtin_amdgcn_mfma_f32_16x16x32_bf16(a0, qreg[1][ks], acc[0][1], 0, 0, 0);
                acc[1][0] = __builtin_amdgcn_mfma_f32_16x16x32_bf16(a1, qreg[0][ks], acc[1][0], 0, 0, 0);
                acc[1][1] = __builtin_amdgcn_mfma_f32_16x16x32_bf16(a1, qreg[1][ks], acc[1][1], 0, 0, 0);
            }
        }
        if (it < nsteps - 1) {
#pragma unroll
            for (int rt = 0; rt < 2; ++rt)
#pragma unroll
                for (int c = 0; c < 2; ++c) {
                    const int col = w * 32 + c * 16 + (l & 15);
                    const int sl = 16 * ((col >> 3) & 3), jb = col & 7;
#pragma unroll
                    for (int r = 0; r < 4; ++r) {
                        const int row15 = (l >> 4) * 4 + r;
                        Sl[cur ^ 1][rt][w][row15 + sl][jb] = (short)f2b(acc[rt][c][r]);
                    }
                }
            __syncthreads();
            cur ^= 1;
        }
    }

    if (outF == nullptr) {
#pragma unroll
        for (int rt = 0; rt < 2; ++rt)
#pragma unroll
            for (int c = 0; c < 2; ++c) {
                const size_t base = (((size_t)grp * 12 + (rt2 * 2 + rt)) * 16 + (2 * w + c)) * 64 + l;
                if (out_bf16) {
                    ushort4 o;
                    o.x = f2b(acc[rt][c][0]); o.y = f2b(acc[rt][c][1]);
                    o.z = f2b(acc[rt][c][2]); o.w = f2b(acc[rt][c][3]);
                    reinterpret_cast<ushort4*>(OutC)[base] = o;
                } else {
                    reinterpret_cast<f32x4*>(OutC)[base] = acc[rt][c];
                }
            }
    } else {
        if (tid < DK) w2l[tid] = W2[tid];
        __syncthreads();   // Sl reads done before resl overlays
#pragma unroll
        for (int rt = 0; rt < 2; ++rt)
#pragma unroll
            for (int c = 0; c < 2; ++c) {
                const int col = w * 32 + c * 16 + (l & 15);
#pragma unroll
                for (int r = 0; r < 4; ++r) {
                    const int row = rt * 16 + (l >> 4) * 4 + r;
                    const int n = rt2 * 32 + row;
                    const float v = acc[rt][c][r] + xin[(size_t)n * DM + col];
                    resl[row][col] = v > 0.f ? v : 0.f;
                }
            }
        __syncthreads();
        const float b2v = *b2p;
        const int k = tid & 255;
        for (int rr = tid >> 8; rr < 32; rr += 2) {
            if (k < OUTW) {
                float o = b2v;
#pragma unroll
                for (int i = 0; i < DK; ++i) o += resl[rr][k + i] * w2l[i];
                outF[(size_t)(rt2 * 32 + rr) * OUTW + k] = sigm(o);
            }
        }
    }
}

// ======================= fp32 FALLBACK PATH (round-2, known-pass) =======================
#define OCB 16
#define ONB 64
#define OR1 24
#define ORB1 8
#define OPSTR 260
#define O_W0T 0u
#define O_W1T 65536u
#define O_PW  131072u
#define O_S   (131072u + 5u*65536u)

__global__ __launch_bounds__(256) void k_prep_o(const float* __restrict__ W, float* __restrict__ ws) {
    const int m = blockIdx.x, k = threadIdx.x;
    const float2 w = *reinterpret_cast<const float2*>(W + (size_t)k * 512 + m * 2);
    ws[O_W0T + m * 256 + k] = w.x;
    ws[O_W1T + m * 256 + k] = w.y;
}

__global__ __launch_bounds__(256) void k_sq_o(const float* __restrict__ A, float* __restrict__ C) {
    __shared__ float ar[4][OPSTR];
    const int r0 = blockIdx.x * 4, k = threadIdx.x;
    for (int r = 0; r < 4; ++r) ar[r][k] = A[(r0 + r) * 256 + k];
    __syncthreads();
    float a0 = 0.f, a1 = 0.f, a2 = 0.f, a3 = 0.f;
    for (int m = 0; m < 256; m += 4) {
        const float p0 = A[(m + 0) * 256 + k], p1 = A[(m + 1) * 256 + k];
        const float p2 = A[(m + 2) * 256 + k], p3 = A[(m + 3) * 256 + k];
        float4 t;
        t = *reinterpret_cast<const float4*>(&ar[0][m]); a0 += t.x * p0 + t.y * p1 + t.z * p2 + t.w * p3;
        t = *reinterpret_cast<const float4*>(&ar[1][m]); a1 += t.x * p0 + t.y * p1 + t.z * p2 + t.w * p3;
        t = *reinterpret_cast<const float4*>(&ar[2][m]); a2 += t.x * p0 + t.y * p1 + t.z * p2 + t.w * p3;
        t = *reinterpret_cast<const float4*>(&ar[3][m]); a3 += t.x * p0 + t.y * p1 + t.z * p2 + t.w * p3;
    }
    C[(r0 + 0) * 256 + k] = a0; C[(r0 + 1) * 256 + k] = a1;
    C[(r0 + 2) * 256 + k] = a2; C[(r0 + 3) * 256 + k] = a3;
}

__global__ __launch_bounds__(256) void k_phase1_o(const float* __restrict__ NAT,
                                                  const float* __restrict__ bvec,
                                                  const float* __restrict__ ws,
                                                  float* __restrict__ Sall) {
    __shared__ float Sl[OR1 * OPSTR];
    __shared__ float Rl[OR1 * OPSTR];
    const int rb = blockIdx.x, bb = blockIdx.y, tid = threadIdx.x;
    const int tj = tid & 63, ti = tid >> 6, n0 = rb * OR1;
    const float* __restrict__ W0t = ws + O_W0T;
    const float* __restrict__ W1t = ws + O_W1T;
    const float4 bv = *reinterpret_cast<const float4*>(bvec + 4 * tj);
    float acc[6][4];
    for (int it = 0; it < OCB; ++it) {
        const int d = bb * OCB + (OCB - 1) - it;
#pragma unroll
        for (int q = 0; q < 6; ++q) {
            const int row = q * 4 + ti;
            const float4 v = *reinterpret_cast<const float4*>(NAT + ((size_t)(n0 + row) * DD + d) * DM + 4 * tj);
            *reinterpret_cast<float4*>(&Rl[row * OPSTR + 4 * tj]) = v;
        }
        __syncthreads();
        if (d == DD - 1) {
#pragma unroll
            for (int r = 0; r < 6; ++r) {
                const float4 v = *reinterpret_cast<const float4*>(&Rl[(ti * 6 + r) * OPSTR + 4 * tj]);
                acc[r][0] = v.x; acc[r][1] = v.y; acc[r][2] = v.z; acc[r][3] = v.w;
            }
        } else {
#pragma unroll
            for (int r = 0; r < 6; ++r) {
                const float4 v = *reinterpret_cast<const float4*>(&Rl[(ti * 6 + r) * OPSTR + 4 * tj]);
                acc[r][0] = bv.x + sigm(v.x); acc[r][1] = bv.y + sigm(v.y);
                acc[r][2] = bv.z + sigm(v.z); acc[r][3] = bv.w + sigm(v.w);
            }
            if (it == 0) {
#pragma unroll 2
                for (int m = 0; m < DM; m += 2) {
                    const float4 w0a = *reinterpret_cast<const float4*>(W0t + m * DM + 4 * tj);
                    const float4 w0b = *reinterpret_cast<const float4*>(W0t + (m + 1) * DM + 4 * tj);
#pragma unroll
                    for (int r = 0; r < 6; ++r) {
                        const float2 rv = *reinterpret_cast<const float2*>(&Rl[(ti * 6 + r) * OPSTR + m]);
                        acc[r][0] += rv.x * w0a.x + rv.y * w0b.x;
                        acc[r][1] += rv.x * w0a.y + rv.y * w0b.y;
                        acc[r][2] += rv.x * w0a.z + rv.y * w0b.z;
                        acc[r][3] += rv.x * w0a.w + rv.y * w0b.w;
                    }
                }
            } else {
#pragma unroll 2
                for (int m = 0; m < DM; m += 2) {
                    const float4 w0a = *reinterpret_cast<const float4*>(W0t + m * DM + 4 * tj);
                    const float4 w0b = *reinterpret_cast<const float4*>(W0t + (m + 1) * DM + 4 * tj);
                    const float4 w1a = *reinterpret_cast<const float4*>(W1t + m * DM + 4 * tj);
                    const float4 w1b = *reinterpret_cast<const float4*>(W1t + (m + 1) * DM + 4 * tj);
#pragma unroll
                    for (int r = 0; r < 6; ++r) {
                        const float2 rv = *reinterpret_cast<const float2*>(&Rl[(ti * 6 + r) * OPSTR + m]);
                        const float2 sv = *reinterpret_cast<const float2*>(&Sl[(ti * 6 + r) * OPSTR + m]);
                        acc[r][0] += rv.x * w0a.x + rv.y * w0b.x + sv.x * w1a.x + sv.y * w1b.x;
                        acc[r][1] += rv.x * w0a.y + rv.y * w0b.y + sv.x * w1a.y + sv.y * w1b.y;
                        acc[r][2] += rv.x * w0a.z + rv.y * w0b.z + sv.x * w1a.z + sv.y * w1b.z;
                        acc[r][3] += rv.x * w0a.w + rv.y * w0b.w + sv.x * w1a.w + sv.y * w1b.w;
                    }
                }
            }
        }
        __syncthreads();
#pragma unroll
        for (int r = 0; r < 6; ++r) {
            float4 v; v.x = acc[r][0]; v.y = acc[r][1]; v.z = acc[r][2]; v.w = acc[r][3];
            *reinterpret_cast<float4*>(&Sl[(ti * 6 + r) * OPSTR + 4 * tj]) = v;
        }
        __syncthreads();
    }
    float* dst = Sall + ((size_t)bb * DN + n0) * DM;
#pragma unroll
    for (int r = 0; r < 6; ++r) {
        float4 v; v.x = acc[r][0]; v.y = acc[r][1]; v.z = acc[r][2]; v.w = acc[r][3];
        *reinterpret_cast<float4*>(dst + (size_t)(ti * 6 + r) * DM + 4 * tj) = v;
    }
}

__global__ __launch_bounds__(256) void k_phase2_o(const float* __restrict__ Sall,
                                                  const float* __restrict__ P,
                                                  const float* __restrict__ x,
                                                  const float* __restrict__ W2,
                                                  const float* __restrict__ b2p,
                                                  float* __restrict__ out) {
    __shared__ float Tl[2][DM];
    __shared__ float resl[DM];
    const int n = blockIdx.x, k = threadIdx.x;
    float a = Sall[((size_t)(ONB - 1) * DN + n) * DM + k];
    Tl[0][k] = a;
    __syncthreads();
    int cur = 0;
    for (int b = ONB - 2; b >= 0; --b) {
        const float s0 = Sall[((size_t)b * DN + n) * DM + k];
        float a0 = 0.f, a1 = 0.f, a2 = 0.f, a3 = 0.f;
        for (int m = 0; m < DM; m += 8) {
            const float4 t0 = *reinterpret_cast<const float4*>(&Tl[cur][m]);
            const float4 t1 = *reinterpret_cast<const float4*>(&Tl[cur][m + 4]);
            a0 += t0.x * P[(m + 0) * DM + k] + t1.x * P[(m + 4) * DM + k];
            a1 += t0.y * P[(m + 1) * DM + k] + t1.y * P[(m + 5) * DM + k];
            a2 += t0.z * P[(m + 2) * DM + k] + t1.z * P[(m + 6) * DM + k];
            a3 += t0.w * P[(m + 3) * DM + k] + t1.w * P[(m + 7) * DM + k];
        }
        a = s0 + ((a0 + a1) + (a2 + a3));
        Tl[cur ^ 1][k] = a;
        __syncthreads();
        cur ^= 1;
    }
    const float b2v = *b2p;
    float r = a + x[(size_t)n * DM + k];
    resl[k] = r > 0.f ? r : 0.f;
    __syncthreads();
    if (k < OUTW) {
        float o = b2v;
#pragma unroll 5
        for (int i = 0; i < DK; ++i) o += resl[k + i] * W2[i];
        out[(size_t)n * OUTW + k] = sigm(o);
    }
}

// ============================= launch =============================
extern "C" void kernel_launch(void* const* d_in, const int* in_sizes, int n_in,
                              void* d_out, int out_size, void* d_ws, size_t ws_size,
                              hipStream_t stream) {
    const float* NAT = (const float*)d_in[0];
    const float* W   = (const float*)d_in[1];
    const float* bv  = (const float*)d_in[2];
    const float* x   = (const float*)d_in[3];
    const float* W2  = (const float*)d_in[4];
    const float* b2  = (const float*)d_in[5];
    float* out = (float*)d_out;
    float* ws  = (float*)d_ws;

    if (ws_size >= MFMA_NEED_BYTES) {
        // ---- MFMA path ----
        k_prep2<<<320, 256, 0, stream>>>(W, ws);

        ushort* SA1 = reinterpret_cast<ushort*>(ws + OFF_SA1);
        float*  SA2 = ws + OFF_SA2;

        // fused phase1 + L1 scan (the big kernel; only needs QB/W0B)
        k_fused<<<dim3(6, 128), 512, 0, stream>>>(NAT, bv, ws, SA1);

        // power chain Q^2..Q^64 (fp32), emitting bf16 B-frags for Q^8 and Q^64
        k_sq256<<<256, 256, 0, stream>>>(ws + OFF_QF,  ws + OFF_A2,  nullptr);
        k_sq256<<<256, 256, 0, stream>>>(ws + OFF_A2,  ws + OFF_A4,  nullptr);
        k_sq256<<<256, 256, 0, stream>>>(ws + OFF_A4,  ws + OFF_A8,
                                         reinterpret_cast<ushort*>(ws + OFF_P8B));
        k_sq256<<<256, 256, 0, stream>>>(ws + OFF_A8,  ws + OFF_A16, nullptr);
        k_sq256<<<256, 256, 0, stream>>>(ws + OFF_A16, ws + OFF_A32, nullptr);
        k_sq256<<<256, 256, 0, stream>>>(ws + OFF_A32, ws + OFF_A64,
                                         reinterpret_cast<ushort*>(ws + OFF_P64B));

        // L2: combine 8 L1 groups per super-group with Q^8 (128 -> 16)
        k_scan<<<dim3(6, 16), 512, 0, stream>>>(SA1, 1, ws, OFF_P8B, 8,
                                                SA2, 0, nullptr, nullptr, nullptr, nullptr);
        // L3: combine 16 super-groups with Q^64, fused epilogue
        k_scan<<<dim3(6, 1), 512, 0, stream>>>(SA2, 0, ws, OFF_P64B, 16,
                                               nullptr, 0, x, W2, b2, out);
    } else {
        // ---- fp32 fallback (round-2, known-pass) ----
        k_prep_o<<<256, 256, 0, stream>>>(W, ws);
        const float* q = ws + O_W1T;
        float* pw = ws + O_PW;
        k_sq_o<<<64, 256, 0, stream>>>(q,              pw + 0 * 65536);
        k_sq_o<<<64, 256, 0, stream>>>(pw + 0 * 65536, pw + 1 * 65536);
        k_sq_o<<<64, 256, 0, stream>>>(pw + 1 * 65536, pw + 2 * 65536);
        k_sq_o<<<64, 256, 0, stream>>>(pw + 2 * 65536, pw + 3 * 65536);
        float* Sall = ws + O_S;
        k_phase1_o<<<dim3(ORB1, ONB), 256, 0, stream>>>(NAT, bv, ws, Sall);
        k_phase2_o<<<192, 256, 0, stream>>>(Sall, pw + 3 * 65536, x, W2, b2, out);
    }
}